// Round 2
// baseline (2839.009 us; speedup 1.0000x reference)
//
#include <hip/hip_runtime.h>
#include <hip/hip_bf16.h>

#define NN 50000
#define EE 500000
#define GG 64
#define IN_F 128
#define H_F 64
#define HEADS 4
#define OUT_F 326000
#define NEG 0.2f

// ---------------- WA precompute: WA[l][j][k] = sum_c W[k][ (j&3)*64+c ] * a[j][c]
// j in 0..3 -> a_src heads, 4..7 -> a_dst heads. One launch, 3 blocks.
struct WAArgs {
    const float* W[3];
    const float* as[3];
    const float* ad[3];
};

__global__ void k_wa(WAArgs A, float* __restrict__ out) {
    int l = blockIdx.x;
    const float* W = A.W[l];
    int t = threadIdx.x;
    for (int o = t; o < 512; o += 256) {
        int j = o >> 6, k = o & 63;
        const float* av = (j < 4) ? (A.as[l] + j * 64) : (A.ad[l] + (j - 4) * 64);
        const float* wr = W + k * 256 + (j & 3) * 64;
        float acc = 0.f;
#pragma unroll
        for (int c = 0; c < 64; ++c) acc += wr[c] * av[c];
        out[l * 512 + j * 64 + k] = acc;
    }
}

// ---------------- embedding GEMM: h0 = x @ W_emb + b_emb ----------------
// block 256 = 4 waves. Tile 32 nodes. Wave `sub` owns k-range [sub*32, sub*32+32).
// Partial dot per (c, sub), 4-way reduce via LDS.
__global__ void k_emb(const float* __restrict__ x, const float* __restrict__ Wemb,
                      const float* __restrict__ bemb, float* __restrict__ h0) {
    __shared__ __attribute__((aligned(16))) float xl[32 * 128];  // 16 KB
    __shared__ float pr[4 * 8 * 64];                             // 8 KB partials
    int t = threadIdx.x;
    int c = t & 63, sub = t >> 6;
    int base = blockIdx.x * 32;

    // stage x tile (coalesced float4)
    const float4* xg = (const float4*)(x + (size_t)base * IN_F);
    float4* xl4 = (float4*)xl;
#pragma unroll
    for (int i = 0; i < 4; ++i) {
        int idx = t + 256 * i;                 // float4 index; node = idx>>5
        int n = base + (idx >> 5);
        xl4[idx] = (n < NN) ? xg[idx] : make_float4(0.f, 0.f, 0.f, 0.f);
    }
    // W chunk for this (c, sub): 32 registers
    float wr[32];
#pragma unroll
    for (int k = 0; k < 32; ++k) wr[k] = Wemb[(sub * 32 + k) * H_F + c];
    float bv = bemb[c];
    __syncthreads();

    // 4 groups of 8 nodes
    for (int g = 0; g < 4; ++g) {
        float acc[8];
#pragma unroll
        for (int j = 0; j < 8; ++j) acc[j] = 0.f;
#pragma unroll
        for (int k4 = 0; k4 < 8; ++k4) {
            float w0 = wr[4 * k4], w1 = wr[4 * k4 + 1], w2 = wr[4 * k4 + 2], w3 = wr[4 * k4 + 3];
#pragma unroll
            for (int j = 0; j < 8; ++j) {
                float4 v = xl4[(g * 8 + j) * 32 + sub * 8 + k4];  // broadcast
                acc[j] += v.x * w0 + v.y * w1 + v.z * w2 + v.w * w3;
            }
        }
        __syncthreads();  // previous group's pr reads done
#pragma unroll
        for (int j = 0; j < 8; ++j) pr[sub * 512 + j * 64 + c] = acc[j];
        __syncthreads();
        // reduce: 512 outputs, 2 per thread; cc == c for both
#pragma unroll
        for (int half = 0; half < 2; ++half) {
            int o = t + half * 256;
            int jj = o >> 6;
            float s = pr[jj * 64 + c] + pr[512 + jj * 64 + c] +
                      pr[1024 + jj * 64 + c] + pr[1536 + jj * 64 + c];
            int n = base + g * 8 + jj;
            if (n < NN) h0[(size_t)n * H_F + c] = s + bv;
        }
    }
}

// ---------------- per-layer GEMM: xbuf = h @ W (pure) ----------------
// thread t owns output column t (wreg[64]); tile 32 nodes staged in LDS.
__global__ void k_gemm_layer(const float* __restrict__ h, const float* __restrict__ W,
                             float* __restrict__ xbuf) {
    __shared__ __attribute__((aligned(16))) float hl[32 * 64];  // 8 KB
    int t = threadIdx.x;
    int base = blockIdx.x * 32;
    const float4* hg = (const float4*)(h + (size_t)base * H_F);
    float4* hl4 = (float4*)hl;
#pragma unroll
    for (int i = 0; i < 2; ++i) {
        int idx = t + 256 * i;                 // float4 idx; node = idx>>4
        int n = base + (idx >> 4);
        hl4[idx] = (n < NN) ? hg[idx] : make_float4(0.f, 0.f, 0.f, 0.f);
    }
    float wr[64];
#pragma unroll
    for (int k = 0; k < 64; ++k) wr[k] = W[k * 256 + t];
    __syncthreads();

    for (int g = 0; g < 8; ++g) {
        float a0 = 0.f, a1 = 0.f, a2 = 0.f, a3 = 0.f;
#pragma unroll
        for (int k4 = 0; k4 < 16; ++k4) {
            float w0 = wr[4 * k4], w1 = wr[4 * k4 + 1], w2 = wr[4 * k4 + 2], w3 = wr[4 * k4 + 3];
            float4 v0 = hl4[(g * 4 + 0) * 16 + k4];
            float4 v1 = hl4[(g * 4 + 1) * 16 + k4];
            float4 v2 = hl4[(g * 4 + 2) * 16 + k4];
            float4 v3 = hl4[(g * 4 + 3) * 16 + k4];
            a0 += v0.x * w0 + v0.y * w1 + v0.z * w2 + v0.w * w3;
            a1 += v1.x * w0 + v1.y * w1 + v1.z * w2 + v1.w * w3;
            a2 += v2.x * w0 + v2.y * w1 + v2.z * w2 + v2.w * w3;
            a3 += v3.x * w0 + v3.y * w1 + v3.z * w2 + v3.w * w3;
        }
        int n = base + g * 4;
        if (n + 0 < NN) xbuf[(size_t)(n + 0) * 256 + t] = a0;
        if (n + 1 < NN) xbuf[(size_t)(n + 1) * 256 + t] = a1;
        if (n + 2 < NN) xbuf[(size_t)(n + 2) * 256 + t] = a2;
        if (n + 3 < NN) xbuf[(size_t)(n + 3) * 256 + t] = a3;
    }
}

// ---------------- logits: ls/ld = h @ WA^T (skinny GEMM, 8 cols) -------------
__global__ void k_logits(const float* __restrict__ h, const float* __restrict__ wa,
                         float* __restrict__ ls, float* __restrict__ ld) {
    __shared__ __attribute__((aligned(16))) float hl[64 * 68];  // padded stride 68
    __shared__ __attribute__((aligned(16))) float wl[8 * 68];
    int t = threadIdx.x;
    int base = blockIdx.x * 64;
    const float4* hg = (const float4*)(h + (size_t)base * H_F);
#pragma unroll
    for (int i = 0; i < 4; ++i) {
        int idx = t + 256 * i;                 // float4 idx; node = idx>>4, k4 = idx&15
        int n = base + (idx >> 4);
        float4 v = (n < NN) ? hg[idx] : make_float4(0.f, 0.f, 0.f, 0.f);
        *(float4*)&hl[(idx >> 4) * 68 + (idx & 15) * 4] = v;
    }
    for (int i = t; i < 512; i += 256) wl[(i >> 6) * 68 + (i & 63)] = wa[i];
    __syncthreads();

#pragma unroll
    for (int half = 0; half < 2; ++half) {
        int o = t + half * 256;
        int n = o >> 3, j = o & 7;
        float acc = 0.f;
#pragma unroll
        for (int k4 = 0; k4 < 16; ++k4) {
            float4 hv = *(const float4*)&hl[n * 68 + k4 * 4];
            float4 wv = *(const float4*)&wl[j * 68 + k4 * 4];
            acc += hv.x * wv.x + hv.y * wv.y + hv.z * wv.z + hv.w * wv.w;
        }
        int gn = base + n;
        if (gn < NN) {
            if (j < 4) ls[gn * HEADS + j] = acc;
            else       ld[gn * HEADS + (j - 4)] = acc;
        }
    }
}

__device__ __forceinline__ float lrelu_exp(float e) {
    e = (e > 0.f) ? e : NEG * e;
    return __expf(e);
}

// ---------------- edge pass 1: denom[dst,h] += exp(lrelu(ls[src]+ld[dst])) ----
__global__ void k_edge_denom(const int* __restrict__ src, const int* __restrict__ dst,
                             const float4* __restrict__ ls4, const float4* __restrict__ ld4,
                             float* __restrict__ den) {
    int i = blockIdx.x * blockDim.x + threadIdx.x;
    if (i >= EE + NN) return;
    int s, d;
    if (i < EE) { s = src[i]; d = dst[i]; } else { s = d = i - EE; }
    float4 a = ls4[s];
    float4 b = ld4[d];
    atomicAdd(&den[d * HEADS + 0], lrelu_exp(a.x + b.x));
    atomicAdd(&den[d * HEADS + 1], lrelu_exp(a.y + b.y));
    atomicAdd(&den[d * HEADS + 2], lrelu_exp(a.z + b.z));
    atomicAdd(&den[d * HEADS + 3], lrelu_exp(a.w + b.w));
}

// ---------------- edge pass 2: acc[dst,c] += (1/4) sum_h alpha[e,h]*x[src,h,c] --
__global__ void k_edge_aggr(const int* __restrict__ src, const int* __restrict__ dst,
                            const float4* __restrict__ ls4, const float4* __restrict__ ld4,
                            const float4* __restrict__ den4, const float* __restrict__ xbuf,
                            float* __restrict__ accb, int totalWaves) {
    int lane = threadIdx.x & 63;
    int wave = (blockIdx.x * blockDim.x + threadIdx.x) >> 6;
    for (int e = wave; e < EE + NN; e += totalWaves) {
        int s, d;
        if (e < EE) { s = src[e]; d = dst[e]; } else { s = d = e - EE; }
        s = __builtin_amdgcn_readfirstlane(s);
        d = __builtin_amdgcn_readfirstlane(d);
        float4 a = ls4[s];
        float4 b = ld4[d];
        float4 dn = den4[d];
        float w0 = lrelu_exp(a.x + b.x) / (dn.x + 1e-16f) * 0.25f;
        float w1 = lrelu_exp(a.y + b.y) / (dn.y + 1e-16f) * 0.25f;
        float w2 = lrelu_exp(a.z + b.z) / (dn.z + 1e-16f) * 0.25f;
        float w3 = lrelu_exp(a.w + b.w) / (dn.w + 1e-16f) * 0.25f;
        const float* xp = xbuf + (size_t)s * (HEADS * H_F);
        float acc = w0 * xp[lane] + w1 * xp[64 + lane] + w2 * xp[128 + lane] + w3 * xp[192 + lane];
        atomicAdd(&accb[(size_t)d * H_F + lane], acc);
    }
}

// ---------------- finalize: h = relu(acc + b), in place, float4 --------------
__global__ void k_finalize(float* __restrict__ h, const float* __restrict__ bias) {
    int i = blockIdx.x * blockDim.x + threadIdx.x;  // float4 index
    if (i >= NN * (H_F / 4)) return;
    float4 v = ((float4*)h)[i];
    float4 b = ((const float4*)bias)[i & 15];
    v.x = fmaxf(v.x + b.x, 0.f);
    v.y = fmaxf(v.y + b.y, 0.f);
    v.z = fmaxf(v.z + b.z, 0.f);
    v.w = fmaxf(v.w + b.w, 0.f);
    ((float4*)h)[i] = v;
}

// ---------------- graph starts via binary search on sorted batch -------------
__global__ void k_starts(const int* __restrict__ batch, int* __restrict__ starts) {
    int g = threadIdx.x;
    if (g > GG) return;
    int lo = 0, hi = NN;
    while (lo < hi) {
        int mid = (lo + hi) >> 1;
        if (batch[mid] < g) lo = mid + 1; else hi = mid;
    }
    starts[g] = lo;
}

// ---------------- pooling: pooledT[c][g] = mean over nodes of graph g --------
__global__ void k_pool(const float* __restrict__ h, const int* __restrict__ starts,
                       float* __restrict__ pooledT) {
    int g = blockIdx.x;
    int s = starts[g], e = starts[g + 1];
    int t = threadIdx.x;
    int c = t & 63, j = t >> 6;
    float sum = 0.f;
    for (int n = s + j; n < e; n += 4) sum += h[(size_t)n * H_F + c];
    __shared__ float lds[256];
    lds[t] = sum;
    __syncthreads();
    if (j == 0) {
        float tot = lds[c] + lds[64 + c] + lds[128 + c] + lds[192 + c];
        int cnt = e - s;
        float inv = 1.0f / (float)(cnt > 0 ? cnt : 1);
        pooledT[c * GG + g] = tot * inv;
    }
}

// ---------------- final FC: out[g,o] = sum_c pooledT[c][g]*Wfc[c,o] + bfc[o] --
__global__ void k_fc(const float* __restrict__ pooledT, const float* __restrict__ Wfc,
                     const float* __restrict__ bfc, float* __restrict__ out) {
    int o = blockIdx.x * blockDim.x + threadIdx.x;
    if (o >= OUT_F) return;
    float acc[GG];
#pragma unroll
    for (int g = 0; g < GG; ++g) acc[g] = 0.f;
    for (int c = 0; c < H_F; ++c) {
        float wvv = Wfc[(size_t)c * OUT_F + o];
        const float* pr = pooledT + c * GG;
#pragma unroll
        for (int g = 0; g < GG; ++g) acc[g] += pr[g] * wvv;
    }
    float bv = bfc[o];
    for (int g = 0; g < GG; ++g) out[(size_t)g * OUT_F + o] = acc[g] + bv;
}

extern "C" void kernel_launch(void* const* d_in, const int* in_sizes, int n_in,
                              void* d_out, int out_size, void* d_ws, size_t ws_size,
                              hipStream_t stream) {
    const float* x      = (const float*)d_in[0];
    const int*   eidx   = (const int*)d_in[1];
    const int*   batch  = (const int*)d_in[3];
    const float* W_emb  = (const float*)d_in[4];
    const float* b_emb  = (const float*)d_in[5];
    const float* W_fc   = (const float*)d_in[6];
    const float* b_fc   = (const float*)d_in[7];
    const float* Wl[3]   = {(const float*)d_in[8],  (const float*)d_in[12], (const float*)d_in[16]};
    const float* asl[3]  = {(const float*)d_in[9],  (const float*)d_in[13], (const float*)d_in[17]};
    const float* adl[3]  = {(const float*)d_in[10], (const float*)d_in[14], (const float*)d_in[18]};
    const float* bl[3]   = {(const float*)d_in[11], (const float*)d_in[15], (const float*)d_in[19]};

    const int* src = eidx;
    const int* dst = eidx + EE;

    // workspace carving
    float* xbuf    = (float*)d_ws;                     // N*256
    float* hA      = xbuf + (size_t)NN * 256;          // N*64
    float* hB      = hA + (size_t)NN * 64;             // N*64
    float* ls      = hB + (size_t)NN * 64;             // N*4
    float* ldb     = ls + (size_t)NN * 4;              // N*4
    float* den     = ldb + (size_t)NN * 4;             // N*4
    float* pooledT = den + (size_t)NN * 4;             // 64*64
    float* wabuf   = pooledT + GG * GG;                // 3*512
    int*   starts  = (int*)(wabuf + 3 * 512);          // 65

    WAArgs wa_args;
    for (int l = 0; l < 3; ++l) { wa_args.W[l] = Wl[l]; wa_args.as[l] = asl[l]; wa_args.ad[l] = adl[l]; }
    k_wa<<<3, 256, 0, stream>>>(wa_args, wabuf);

    k_emb<<<(NN + 31) / 32, 256, 0, stream>>>(x, W_emb, b_emb, hA);

    float* hcur = hA;
    float* hnext = hB;
    for (int l = 0; l < 3; ++l) {
        k_gemm_layer<<<(NN + 31) / 32, 256, 0, stream>>>(hcur, Wl[l], xbuf);
        k_logits<<<(NN + 63) / 64, 256, 0, stream>>>(hcur, wabuf + l * 512, ls, ldb);
        hipMemsetAsync(den, 0, (size_t)NN * 4 * sizeof(float), stream);
        hipMemsetAsync(hnext, 0, (size_t)NN * 64 * sizeof(float), stream);
        k_edge_denom<<<(EE + NN + 255) / 256, 256, 0, stream>>>(
            src, dst, (const float4*)ls, (const float4*)ldb, den);
        const int aggrBlocks = 2048;
        k_edge_aggr<<<aggrBlocks, 256, 0, stream>>>(
            src, dst, (const float4*)ls, (const float4*)ldb, (const float4*)den,
            xbuf, hnext, aggrBlocks * 4);
        k_finalize<<<(NN * 16 + 255) / 256, 256, 0, stream>>>(hnext, bl[l]);
        float* tmp = hcur; hcur = hnext; hnext = tmp;
    }

    k_starts<<<1, 128, 0, stream>>>(batch, starts);
    k_pool<<<GG, 256, 0, stream>>>(hcur, starts, pooledT);
    k_fc<<<(OUT_F + 255) / 256, 256, 0, stream>>>(pooledT, W_fc, b_fc, (float*)d_out);
}

// Round 3
// 1463.490 us; speedup vs baseline: 1.9399x; 1.9399x over previous
//
#include <hip/hip_runtime.h>
#include <hip/hip_bf16.h>

#define NN 50000
#define EE 500000
#define GG 64
#define IN_F 128
#define H_F 64
#define HEADS 4
#define OUT_F 326000
#define NEG 0.2f

// ---------------- WA precompute: WA[l][j][k] = sum_c W[k][ (j&3)*64+c ] * a[j][c]
struct WAArgs {
    const float* W[3];
    const float* as[3];
    const float* ad[3];
};

__global__ __launch_bounds__(256, 2) void k_wa(WAArgs A, float* __restrict__ out) {
    int l = blockIdx.x;
    const float* W = A.W[l];
    int t = threadIdx.x;
    for (int o = t; o < 512; o += 256) {
        int j = o >> 6, k = o & 63;
        const float* av = (j < 4) ? (A.as[l] + j * 64) : (A.ad[l] + (j - 4) * 64);
        const float* wr = W + k * 256 + (j & 3) * 64;
        float acc = 0.f;
#pragma unroll
        for (int c = 0; c < 64; ++c) acc += wr[c] * av[c];
        out[l * 512 + j * 64 + k] = acc;
    }
}

// ---------------- embedding GEMM: h0 = x @ W_emb + b_emb ----------------
// block 256 = 4 waves. Tile 32 nodes. Wave `sub` owns k-range [sub*32, sub*32+32).
__global__ __launch_bounds__(256, 2) void k_emb(const float* __restrict__ x,
                                                const float* __restrict__ Wemb,
                                                const float* __restrict__ bemb,
                                                float* __restrict__ h0) {
    __shared__ __attribute__((aligned(16))) float xl[32 * 128];  // 16 KB
    __shared__ float pr[4 * 8 * 64];                             // 8 KB partials
    int t = threadIdx.x;
    int c = t & 63, sub = t >> 6;
    int base = blockIdx.x * 32;

    const float4* xg = (const float4*)(x + (size_t)base * IN_F);
    float4* xl4 = (float4*)xl;
#pragma unroll
    for (int i = 0; i < 4; ++i) {
        int idx = t + 256 * i;                 // float4 index; node = idx>>5
        int n = base + (idx >> 5);
        xl4[idx] = (n < NN) ? xg[idx] : make_float4(0.f, 0.f, 0.f, 0.f);
    }
    float wr[32];
#pragma unroll
    for (int k = 0; k < 32; ++k) wr[k] = Wemb[(sub * 32 + k) * H_F + c];
    float bv = bemb[c];
    __syncthreads();

    for (int g = 0; g < 4; ++g) {
        float acc[8];
#pragma unroll
        for (int j = 0; j < 8; ++j) acc[j] = 0.f;
#pragma unroll
        for (int k4 = 0; k4 < 8; ++k4) {
            float w0 = wr[4 * k4], w1 = wr[4 * k4 + 1], w2 = wr[4 * k4 + 2], w3 = wr[4 * k4 + 3];
#pragma unroll
            for (int j = 0; j < 8; ++j) {
                float4 v = xl4[(g * 8 + j) * 32 + sub * 8 + k4];  // broadcast
                acc[j] += v.x * w0 + v.y * w1 + v.z * w2 + v.w * w3;
            }
        }
        __syncthreads();
#pragma unroll
        for (int j = 0; j < 8; ++j) pr[sub * 512 + j * 64 + c] = acc[j];
        __syncthreads();
#pragma unroll
        for (int half = 0; half < 2; ++half) {
            int o = t + half * 256;
            int jj = o >> 6;
            float s = pr[jj * 64 + c] + pr[512 + jj * 64 + c] +
                      pr[1024 + jj * 64 + c] + pr[1536 + jj * 64 + c];
            int n = base + g * 8 + jj;
            if (n < NN) h0[(size_t)n * H_F + c] = s + bv;
        }
    }
}

// ---------------- per-layer GEMM: xbuf = h @ W (pure) ----------------
// thread t owns output column t (wr[64] in registers); tile 32 nodes in LDS.
__global__ __launch_bounds__(256, 2) void k_gemm_layer(const float* __restrict__ h,
                                                       const float* __restrict__ W,
                                                       float* __restrict__ xbuf) {
    __shared__ __attribute__((aligned(16))) float hl[32 * 64];  // 8 KB
    int t = threadIdx.x;
    int base = blockIdx.x * 32;
    const float4* hg = (const float4*)(h + (size_t)base * H_F);
    float4* hl4 = (float4*)hl;
#pragma unroll
    for (int i = 0; i < 2; ++i) {
        int idx = t + 256 * i;                 // float4 idx; node = idx>>4
        int n = base + (idx >> 4);
        hl4[idx] = (n < NN) ? hg[idx] : make_float4(0.f, 0.f, 0.f, 0.f);
    }
    float wr[64];
#pragma unroll
    for (int k = 0; k < 64; ++k) wr[k] = W[k * 256 + t];
    __syncthreads();

    for (int g = 0; g < 8; ++g) {
        float a0 = 0.f, a1 = 0.f, a2 = 0.f, a3 = 0.f;
#pragma unroll
        for (int k4 = 0; k4 < 16; ++k4) {
            float w0 = wr[4 * k4], w1 = wr[4 * k4 + 1], w2 = wr[4 * k4 + 2], w3 = wr[4 * k4 + 3];
            float4 v0 = hl4[(g * 4 + 0) * 16 + k4];
            float4 v1 = hl4[(g * 4 + 1) * 16 + k4];
            float4 v2 = hl4[(g * 4 + 2) * 16 + k4];
            float4 v3 = hl4[(g * 4 + 3) * 16 + k4];
            a0 += v0.x * w0 + v0.y * w1 + v0.z * w2 + v0.w * w3;
            a1 += v1.x * w0 + v1.y * w1 + v1.z * w2 + v1.w * w3;
            a2 += v2.x * w0 + v2.y * w1 + v2.z * w2 + v2.w * w3;
            a3 += v3.x * w0 + v3.y * w1 + v3.z * w2 + v3.w * w3;
        }
        int n = base + g * 4;
        if (n + 0 < NN) xbuf[(size_t)(n + 0) * 256 + t] = a0;
        if (n + 1 < NN) xbuf[(size_t)(n + 1) * 256 + t] = a1;
        if (n + 2 < NN) xbuf[(size_t)(n + 2) * 256 + t] = a2;
        if (n + 3 < NN) xbuf[(size_t)(n + 3) * 256 + t] = a3;
    }
}

// ---------------- logits: ls/ld = h @ WA^T (skinny GEMM, 8 cols) -------------
__global__ __launch_bounds__(256, 2) void k_logits(const float* __restrict__ h,
                                                   const float* __restrict__ wa,
                                                   float* __restrict__ ls,
                                                   float* __restrict__ ld) {
    __shared__ __attribute__((aligned(16))) float hl[64 * 68];  // padded stride 68
    __shared__ __attribute__((aligned(16))) float wl[8 * 68];
    int t = threadIdx.x;
    int base = blockIdx.x * 64;
    const float4* hg = (const float4*)(h + (size_t)base * H_F);
#pragma unroll
    for (int i = 0; i < 4; ++i) {
        int idx = t + 256 * i;                 // float4 idx; node = idx>>4, k4 = idx&15
        int n = base + (idx >> 4);
        float4 v = (n < NN) ? hg[idx] : make_float4(0.f, 0.f, 0.f, 0.f);
        *(float4*)&hl[(idx >> 4) * 68 + (idx & 15) * 4] = v;
    }
    for (int i = t; i < 512; i += 256) wl[(i >> 6) * 68 + (i & 63)] = wa[i];
    __syncthreads();

#pragma unroll
    for (int half = 0; half < 2; ++half) {
        int o = t + half * 256;
        int n = o >> 3, j = o & 7;
        float acc = 0.f;
#pragma unroll
        for (int k4 = 0; k4 < 16; ++k4) {
            float4 hv = *(const float4*)&hl[n * 68 + k4 * 4];
            float4 wv = *(const float4*)&wl[j * 68 + k4 * 4];
            acc += hv.x * wv.x + hv.y * wv.y + hv.z * wv.z + hv.w * wv.w;
        }
        int gn = base + n;
        if (gn < NN) {
            if (j < 4) ls[gn * HEADS + j] = acc;
            else       ld[gn * HEADS + (j - 4)] = acc;
        }
    }
}

__device__ __forceinline__ float lrelu_exp(float e) {
    e = (e > 0.f) ? e : NEG * e;
    return __expf(e);
}

// ---------------- edge pass 1: denom[dst,h] += exp(lrelu(ls[src]+ld[dst])) ----
__global__ __launch_bounds__(256, 4) void k_edge_denom(const int* __restrict__ src,
                                                       const int* __restrict__ dst,
                                                       const float4* __restrict__ ls4,
                                                       const float4* __restrict__ ld4,
                                                       float* __restrict__ den) {
    int i = blockIdx.x * blockDim.x + threadIdx.x;
    if (i >= EE + NN) return;
    int s, d;
    if (i < EE) { s = src[i]; d = dst[i]; } else { s = d = i - EE; }
    float4 a = ls4[s];
    float4 b = ld4[d];
    atomicAdd(&den[d * HEADS + 0], lrelu_exp(a.x + b.x));
    atomicAdd(&den[d * HEADS + 1], lrelu_exp(a.y + b.y));
    atomicAdd(&den[d * HEADS + 2], lrelu_exp(a.z + b.z));
    atomicAdd(&den[d * HEADS + 3], lrelu_exp(a.w + b.w));
}

// ---------------- edge pass 2: acc[dst,c] += (1/4) sum_h alpha[e,h]*x[src,h,c] --
__global__ __launch_bounds__(256, 4) void k_edge_aggr(const int* __restrict__ src,
                                                      const int* __restrict__ dst,
                                                      const float4* __restrict__ ls4,
                                                      const float4* __restrict__ ld4,
                                                      const float4* __restrict__ den4,
                                                      const float* __restrict__ xbuf,
                                                      float* __restrict__ accb, int totalWaves) {
    int lane = threadIdx.x & 63;
    int wave = (blockIdx.x * blockDim.x + threadIdx.x) >> 6;
    for (int e = wave; e < EE + NN; e += totalWaves) {
        int s, d;
        if (e < EE) { s = src[e]; d = dst[e]; } else { s = d = e - EE; }
        s = __builtin_amdgcn_readfirstlane(s);
        d = __builtin_amdgcn_readfirstlane(d);
        float4 a = ls4[s];
        float4 b = ld4[d];
        float4 dn = den4[d];
        float w0 = lrelu_exp(a.x + b.x) / (dn.x + 1e-16f) * 0.25f;
        float w1 = lrelu_exp(a.y + b.y) / (dn.y + 1e-16f) * 0.25f;
        float w2 = lrelu_exp(a.z + b.z) / (dn.z + 1e-16f) * 0.25f;
        float w3 = lrelu_exp(a.w + b.w) / (dn.w + 1e-16f) * 0.25f;
        const float* xp = xbuf + (size_t)s * (HEADS * H_F);
        float acc = w0 * xp[lane] + w1 * xp[64 + lane] + w2 * xp[128 + lane] + w3 * xp[192 + lane];
        atomicAdd(&accb[(size_t)d * H_F + lane], acc);
    }
}

// ---------------- finalize: h = relu(acc + b), in place, float4 --------------
__global__ __launch_bounds__(256, 4) void k_finalize(float* __restrict__ h,
                                                     const float* __restrict__ bias) {
    int i = blockIdx.x * blockDim.x + threadIdx.x;  // float4 index
    if (i >= NN * (H_F / 4)) return;
    float4 v = ((float4*)h)[i];
    float4 b = ((const float4*)bias)[i & 15];
    v.x = fmaxf(v.x + b.x, 0.f);
    v.y = fmaxf(v.y + b.y, 0.f);
    v.z = fmaxf(v.z + b.z, 0.f);
    v.w = fmaxf(v.w + b.w, 0.f);
    ((float4*)h)[i] = v;
}

// ---------------- graph starts via binary search on sorted batch -------------
__global__ __launch_bounds__(128, 1) void k_starts(const int* __restrict__ batch,
                                                   int* __restrict__ starts) {
    int g = threadIdx.x;
    if (g > GG) return;
    int lo = 0, hi = NN;
    while (lo < hi) {
        int mid = (lo + hi) >> 1;
        if (batch[mid] < g) lo = mid + 1; else hi = mid;
    }
    starts[g] = lo;
}

// ---------------- pooling: pooledT[c][g] = mean over nodes of graph g --------
__global__ __launch_bounds__(256, 2) void k_pool(const float* __restrict__ h,
                                                 const int* __restrict__ starts,
                                                 float* __restrict__ pooledT) {
    int g = blockIdx.x;
    int s = starts[g], e = starts[g + 1];
    int t = threadIdx.x;
    int c = t & 63, j = t >> 6;
    float sum = 0.f;
    for (int n = s + j; n < e; n += 4) sum += h[(size_t)n * H_F + c];
    __shared__ float lds[256];
    lds[t] = sum;
    __syncthreads();
    if (j == 0) {
        float tot = lds[c] + lds[64 + c] + lds[128 + c] + lds[192 + c];
        int cnt = e - s;
        float inv = 1.0f / (float)(cnt > 0 ? cnt : 1);
        pooledT[c * GG + g] = tot * inv;
    }
}

// ---------------- final FC: out[g,o] = sum_c pooledT[c][g]*Wfc[c,o] + bfc[o] --
__global__ __launch_bounds__(256, 2) void k_fc(const float* __restrict__ pooledT,
                                               const float* __restrict__ Wfc,
                                               const float* __restrict__ bfc,
                                               float* __restrict__ out) {
    int o = blockIdx.x * blockDim.x + threadIdx.x;
    if (o >= OUT_F) return;
    float acc[GG];
#pragma unroll
    for (int g = 0; g < GG; ++g) acc[g] = 0.f;
    for (int c = 0; c < H_F; ++c) {
        float wvv = Wfc[(size_t)c * OUT_F + o];
        const float* pr = pooledT + c * GG;
#pragma unroll
        for (int g = 0; g < GG; ++g) acc[g] += pr[g] * wvv;
    }
    float bv = bfc[o];
    for (int g = 0; g < GG; ++g) out[(size_t)g * OUT_F + o] = acc[g] + bv;
}

extern "C" void kernel_launch(void* const* d_in, const int* in_sizes, int n_in,
                              void* d_out, int out_size, void* d_ws, size_t ws_size,
                              hipStream_t stream) {
    const float* x      = (const float*)d_in[0];
    const int*   eidx   = (const int*)d_in[1];
    const int*   batch  = (const int*)d_in[3];
    const float* W_emb  = (const float*)d_in[4];
    const float* b_emb  = (const float*)d_in[5];
    const float* W_fc   = (const float*)d_in[6];
    const float* b_fc   = (const float*)d_in[7];
    const float* Wl[3]   = {(const float*)d_in[8],  (const float*)d_in[12], (const float*)d_in[16]};
    const float* asl[3]  = {(const float*)d_in[9],  (const float*)d_in[13], (const float*)d_in[17]};
    const float* adl[3]  = {(const float*)d_in[10], (const float*)d_in[14], (const float*)d_in[18]};
    const float* bl[3]   = {(const float*)d_in[11], (const float*)d_in[15], (const float*)d_in[19]};

    const int* src = eidx;
    const int* dst = eidx + EE;

    // workspace carving
    float* xbuf    = (float*)d_ws;                     // N*256
    float* hA      = xbuf + (size_t)NN * 256;          // N*64
    float* hB      = hA + (size_t)NN * 64;             // N*64
    float* ls      = hB + (size_t)NN * 64;             // N*4
    float* ldb     = ls + (size_t)NN * 4;              // N*4
    float* den     = ldb + (size_t)NN * 4;             // N*4
    float* pooledT = den + (size_t)NN * 4;             // 64*64
    float* wabuf   = pooledT + GG * GG;                // 3*512
    int*   starts  = (int*)(wabuf + 3 * 512);          // 65

    WAArgs wa_args;
    for (int l = 0; l < 3; ++l) { wa_args.W[l] = Wl[l]; wa_args.as[l] = asl[l]; wa_args.ad[l] = adl[l]; }
    k_wa<<<3, 256, 0, stream>>>(wa_args, wabuf);

    k_emb<<<(NN + 31) / 32, 256, 0, stream>>>(x, W_emb, b_emb, hA);

    float* hcur = hA;
    float* hnext = hB;
    for (int l = 0; l < 3; ++l) {
        k_gemm_layer<<<(NN + 31) / 32, 256, 0, stream>>>(hcur, Wl[l], xbuf);
        k_logits<<<(NN + 63) / 64, 256, 0, stream>>>(hcur, wabuf + l * 512, ls, ldb);
        hipMemsetAsync(den, 0, (size_t)NN * 4 * sizeof(float), stream);
        hipMemsetAsync(hnext, 0, (size_t)NN * 64 * sizeof(float), stream);
        k_edge_denom<<<(EE + NN + 255) / 256, 256, 0, stream>>>(
            src, dst, (const float4*)ls, (const float4*)ldb, den);
        const int aggrBlocks = 2048;
        k_edge_aggr<<<aggrBlocks, 256, 0, stream>>>(
            src, dst, (const float4*)ls, (const float4*)ldb, (const float4*)den,
            xbuf, hnext, aggrBlocks * 4);
        k_finalize<<<(NN * 16 + 255) / 256, 256, 0, stream>>>(hnext, bl[l]);
        float* tmp = hcur; hcur = hnext; hnext = tmp;
    }

    k_starts<<<1, 128, 0, stream>>>(batch, starts);
    k_pool<<<GG, 256, 0, stream>>>(hcur, starts, pooledT);
    k_fc<<<(OUT_F + 255) / 256, 256, 0, stream>>>(pooledT, W_fc, b_fc, (float*)d_out);
}